// Round 3
// baseline (749.087 us; speedup 1.0000x reference)
//
#include <hip/hip_runtime.h>
#include <math.h>
#include <string.h>

#define B_   2048
#define TT   128
#define TA   256
#define TV   256
#define CT   300
#define CA   74
#define CV   35
#define D    64
#define E_   4
#define R_   8
#define H_   4
#define L_   4
#define NC   7
#define POOLW 416  // 409 padded to 16B multiple

// All INPUTS are float32 (reference dtype; confirmed: bf16 reads gave NaN previously).
// OUTPUT buffer is float32. Params = 50 const pointers in setup_inputs() order, then out.
struct Params {
  const float *text, *audio, *video;
  const float *text_w, *text_b, *text_ln_g, *text_ln_b;
  const float *audio_w, *audio_b, *audio_ln_g, *audio_ln_b;
  const float *video_w, *video_b, *video_ln_g, *video_ln_b;
  const float *latent;
  const float *wq, *bq, *wk, *bk, *wv, *bv, *wo, *bo;
  const float *n1_g, *n1_b, *ffn_w1, *ffn_b1, *ffn_w2, *ffn_b2, *n2_g, *n2_b;
  const float *r_w1, *r_b1, *r_ln_g, *r_ln_b, *r_w2, *r_b2;
  const float *p1_w, *p1_b, *p2_w, *p2_b;
  const float *lora_down, *lora_up;
  const float *c_ln_g, *c_ln_b, *c_w1, *c_b1, *c_w2, *c_b2;
  float *out;
};

__device__ __forceinline__ float wsum(float v) {
#pragma unroll
  for (int m = 32; m >= 1; m >>= 1) v += __shfl_xor(v, m, 64);
  return v;
}
__device__ __forceinline__ float hsum16(float v) {
#pragma unroll
  for (int m = 8; m >= 1; m >>= 1) v += __shfl_xor(v, m, 64);
  return v;
}
__device__ __forceinline__ void acc4(float4& a, const float4 v) {
  a.x += v.x; a.y += v.y; a.z += v.z; a.w += v.w;
}
__device__ __forceinline__ void acc2f(float2& a, const float2 v) { a.x += v.x; a.y += v.y; }
#define WB() __builtin_amdgcn_wave_barrier()

// ---------------- LDS overlay arena (34304 B). Lifetimes:
//  pool phase : sbufT[0,14400) sbufA[14400,21504) sbufV[21504,25424)  (dead after reduce barrier)
//               s_pool[25424,32080) (dead after modality proj)        s_q[33280,34304)
//  head phase : s_z[0,3072) s_k[3072,6144) s_ao[6144,10240) s_lat1T[10240,14336)
//               s_h1[14336,30720)  (written only after barrier #1 -> s_pool dead)
//               s_lat2[6144,10240) (over s_ao, written after barrier #2)
//               s_f[30720,31744) s_down[31744,32256) s_cl[32256,33280) (after barrier #3)
#define SBT(g, s, c)  sbufT[((g) * 4 + (s)) * 75 + (c)]
#define SBA(g, s, c)  sbufA[((g) * 4 + (s)) * 37 + (c)]
#define SBV(g, s, c)  sbufV[((g) * 4 + (s)) * 35 + (c)]
#define SP(s, i)      s_pool[(s) * POOLW + (i)]
#define SZI(s, i)     s_z[(s) * 192 + (i)]
#define SKI(s, i)     s_k[(s) * 192 + (i)]
#define SAO(s, i)     s_ao[(s) * 256 + (i)]
#define SL1(s, i, l)  s_lat1T[(((s) * 64 + (i)) << 2) + (l)]   // [sample][col][latent]
#define SH1(s, c, l)  s_h1[(((s) * 256 + (c)) << 2) + (l)]     // [sample][col][latent]
#define SL2(s, l, j)  s_lat2[(((s) * 4 + (l)) << 6) + (j)]
#define SF(s, i)      s_f[(s) * 64 + (i)]
#define SDN(s, i)     s_down[(s) * 32 + (i)]
#define SCL(s, i)     s_cl[(s) * 64 + (i)]

// 512 threads = 8 waves, 4 samples per block, grid 512 -> 2 blocks/CU, 16 waves/CU.
__global__ __launch_bounds__(512, 4) void fused_kernel(Params p) {
  const int tid = threadIdx.x;
  const int lane = tid & 63;
  const int w = tid >> 6;          // 0..7
  const int b0 = blockIdx.x * 4;

  __shared__ __align__(16) unsigned char smem_raw[34304];
  float4* const sbufT   = reinterpret_cast<float4*>(smem_raw);
  float2* const sbufA   = reinterpret_cast<float2*>(smem_raw + 14400);
  float*  const sbufV   = reinterpret_cast<float*>(smem_raw + 21504);
  float*  const s_pool  = reinterpret_cast<float*>(smem_raw + 25424);
  float*  const s_q     = reinterpret_cast<float*>(smem_raw + 33280);
  float*  const s_z     = reinterpret_cast<float*>(smem_raw);
  float*  const s_k     = reinterpret_cast<float*>(smem_raw + 3072);
  float*  const s_ao    = reinterpret_cast<float*>(smem_raw + 6144);
  float*  const s_lat1T = reinterpret_cast<float*>(smem_raw + 10240);
  float*  const s_h1    = reinterpret_cast<float*>(smem_raw + 14336);
  float*  const s_lat2  = reinterpret_cast<float*>(smem_raw + 6144);
  float*  const s_f     = reinterpret_cast<float*>(smem_raw + 30720);
  float*  const s_down  = reinterpret_cast<float*>(smem_raw + 31744);
  float*  const s_cl    = reinterpret_cast<float*>(smem_raw + 32256);

  // ============== phase 1: streaming loads; waves 0-3 text, waves 4-7 audio+video ==============
  if (tid < 256) {
    // text: 75 f4-cols x 3 row-groups; rows stride 1200B (16B aligned); x4 unrolled (16 loads in flight)
    const int c4 = tid % 75, g = tid / 75;
    if (g < 3) {
      float4 accT[4];
      const float* tp[4];
#pragma unroll
      for (int s = 0; s < 4; ++s) {
        accT[s] = make_float4(0.f, 0.f, 0.f, 0.f);
        tp[s] = p.text + (size_t)(b0 + s) * (TT * CT) + 4 * c4;
      }
      int t = g;
      for (; t + 9 < TT; t += 12) {
        float4 u[4][4];
#pragma unroll
        for (int s = 0; s < 4; ++s)
#pragma unroll
          for (int k = 0; k < 4; ++k)
            u[s][k] = *reinterpret_cast<const float4*>(tp[s] + (size_t)(t + 3 * k) * CT);
#pragma unroll
        for (int s = 0; s < 4; ++s)
#pragma unroll
          for (int k = 0; k < 4; ++k) acc4(accT[s], u[s][k]);
      }
      for (; t + 3 < TT; t += 6) {
        float4 u[4][2];
#pragma unroll
        for (int s = 0; s < 4; ++s)
#pragma unroll
          for (int k = 0; k < 2; ++k)
            u[s][k] = *reinterpret_cast<const float4*>(tp[s] + (size_t)(t + 3 * k) * CT);
#pragma unroll
        for (int s = 0; s < 4; ++s) { acc4(accT[s], u[s][0]); acc4(accT[s], u[s][1]); }
      }
      for (; t < TT; t += 3) {
#pragma unroll
        for (int s = 0; s < 4; ++s)
          acc4(accT[s], *reinterpret_cast<const float4*>(tp[s] + (size_t)t * CT));
      }
#pragma unroll
      for (int s = 0; s < 4; ++s) SBT(g, s, c4) = accT[s];
    }
    // q = latent @ wq + bq (b-independent): tid = l*64 + j
    {
      const int l = tid >> 6, j = tid & 63;
      float acc = p.bq[j];
      for (int i = 0; i < D; ++i) acc += p.latent[l * D + i] * p.wq[i * D + j];
      s_q[tid] = acc;
    }
  } else {
    const int tid2 = tid - 256;
    // audio: 37 f2-cols x 6 row-groups; rows stride 296B (8B aligned); x4 unrolled
    const int c2 = tid2 % 37, ga = tid2 / 37;
    if (ga < 6) {
      float2 accA[4];
      const float* ap[4];
#pragma unroll
      for (int s = 0; s < 4; ++s) {
        accA[s] = make_float2(0.f, 0.f);
        ap[s] = p.audio + (size_t)(b0 + s) * (TA * CA) + 2 * c2;
      }
      int t = ga;
      for (; t + 18 < TA; t += 24) {
        float2 u[4][4];
#pragma unroll
        for (int s = 0; s < 4; ++s)
#pragma unroll
          for (int k = 0; k < 4; ++k)
            u[s][k] = *reinterpret_cast<const float2*>(ap[s] + (size_t)(t + 6 * k) * CA);
#pragma unroll
        for (int s = 0; s < 4; ++s)
#pragma unroll
          for (int k = 0; k < 4; ++k) acc2f(accA[s], u[s][k]);
      }
      for (; t + 6 < TA; t += 12) {
        float2 u[4][2];
#pragma unroll
        for (int s = 0; s < 4; ++s)
#pragma unroll
          for (int k = 0; k < 2; ++k)
            u[s][k] = *reinterpret_cast<const float2*>(ap[s] + (size_t)(t + 6 * k) * CA);
#pragma unroll
        for (int s = 0; s < 4; ++s) { acc2f(accA[s], u[s][0]); acc2f(accA[s], u[s][1]); }
      }
      for (; t < TA; t += 6) {
#pragma unroll
        for (int s = 0; s < 4; ++s)
          acc2f(accA[s], *reinterpret_cast<const float2*>(ap[s] + (size_t)t * CA));
      }
#pragma unroll
      for (int s = 0; s < 4; ++s) SBA(ga, s, c2) = accA[s];
    }
    // video: 35 cols x 7 row-groups; scalar; x4 unrolled
    const int cv = tid2 % 35, gv = tid2 / 35;
    if (gv < 7) {
      float accV[4] = {0.f, 0.f, 0.f, 0.f};
      const float* vp[4];
#pragma unroll
      for (int s = 0; s < 4; ++s) vp[s] = p.video + (size_t)(b0 + s) * (TV * CV) + cv;
      int t = gv;
      for (; t + 21 < TV; t += 28) {
        float u[4][4];
#pragma unroll
        for (int s = 0; s < 4; ++s)
#pragma unroll
          for (int k = 0; k < 4; ++k) u[s][k] = vp[s][(size_t)(t + 7 * k) * CV];
#pragma unroll
        for (int s = 0; s < 4; ++s)
#pragma unroll
          for (int k = 0; k < 4; ++k) accV[s] += u[s][k];
      }
      for (; t + 7 < TV; t += 14) {
        float u[4][2];
#pragma unroll
        for (int s = 0; s < 4; ++s)
#pragma unroll
          for (int k = 0; k < 2; ++k) u[s][k] = vp[s][(size_t)(t + 7 * k) * CV];
#pragma unroll
        for (int s = 0; s < 4; ++s) { accV[s] += u[s][0]; accV[s] += u[s][1]; }
      }
      for (; t < TV; t += 7) {
#pragma unroll
        for (int s = 0; s < 4; ++s) accV[s] += vp[s][(size_t)t * CV];
      }
#pragma unroll
      for (int s = 0; s < 4; ++s) SBV(gv, s, cv) = accV[s];
    }
  }
  __syncthreads();

  // ============== reduce partials -> s_pool (same order as before: g ascending) ==============
  if (tid < 75) {
#pragma unroll
    for (int s = 0; s < 4; ++s) {
      float4 a = SBT(0, s, tid), bb = SBT(1, s, tid), c = SBT(2, s, tid);
      float4 r;
      r.x = (a.x + bb.x + c.x) * (1.f / TT);
      r.y = (a.y + bb.y + c.y) * (1.f / TT);
      r.z = (a.z + bb.z + c.z) * (1.f / TT);
      r.w = (a.w + bb.w + c.w) * (1.f / TT);
      *reinterpret_cast<float4*>(&SP(s, 4 * tid)) = r;
    }
  } else if (tid < 112) {
    const int c2 = tid - 75;
#pragma unroll
    for (int s = 0; s < 4; ++s) {
      float2 r = make_float2(0.f, 0.f);
#pragma unroll
      for (int g = 0; g < 6; ++g) acc2f(r, SBA(g, s, c2));
      r.x *= (1.f / TA); r.y *= (1.f / TA);
      *reinterpret_cast<float2*>(&SP(s, CT + 2 * c2)) = r;
    }
  } else if (tid < 147) {
    const int c = tid - 112;
#pragma unroll
    for (int s = 0; s < 4; ++s) {
      float r = 0.f;
#pragma unroll
      for (int g = 0; g < 7; ++g) r += SBV(g, s, c);
      SP(s, CT + CA + c) = r * (1.f / TV);
    }
  }
  __syncthreads();

  // ============== head: waves 0-3 run per-sample chains; 4-7 idle until FFN co-op ==============
  float fl = 0.f, w0 = 0.f, w1 = 0.f, w2 = 0.f, w3 = 0.f;

  if (w < 4) {
    const int b = b0 + w;
    (void)b;
    // ---- modality projections + LN + ReLU ----
    {
      float acc = p.text_b[lane];
#pragma unroll 4
      for (int i = 0; i < CT; ++i) acc += SP(w, i) * p.text_w[i * D + lane];
      float mu = wsum(acc) * (1.f / D);
      float d = acc - mu;
      float var = wsum(d * d) * (1.f / D);
      SZI(w, 0 * D + lane) =
          fmaxf(d * rsqrtf(var + 1e-5f) * p.text_ln_g[lane] + p.text_ln_b[lane], 0.f);

      acc = p.audio_b[lane];
#pragma unroll 4
      for (int i = 0; i < CA; ++i) acc += SP(w, CT + i) * p.audio_w[i * D + lane];
      mu = wsum(acc) * (1.f / D); d = acc - mu; var = wsum(d * d) * (1.f / D);
      SZI(w, 1 * D + lane) =
          fmaxf(d * rsqrtf(var + 1e-5f) * p.audio_ln_g[lane] + p.audio_ln_b[lane], 0.f);

      acc = p.video_b[lane];
#pragma unroll 4
      for (int i = 0; i < CV; ++i) acc += SP(w, CT + CA + i) * p.video_w[i * D + lane];
      mu = wsum(acc) * (1.f / D); d = acc - mu; var = wsum(d * d) * (1.f / D);
      SZI(w, 2 * D + lane) =
          fmaxf(d * rsqrtf(var + 1e-5f) * p.video_ln_g[lane] + p.video_ln_b[lane], 0.f);
    }
    WB();

    // ---- k, v projections (v stays in registers) ----
    float vreg[3];
#pragma unroll
    for (int s = 0; s < 3; ++s) {
      float ak = p.bk[lane], av = p.bv[lane];
#pragma unroll 4
      for (int i = 0; i < D; ++i) {
        float z = SZI(w, s * D + i);
        ak += z * p.wk[i * D + lane];
        av += z * p.wv[i * D + lane];
      }
      SKI(w, s * D + lane) = ak;
      vreg[s] = av;
    }
    WB();

    // ---- scores (16-lane-group dots) + softmax over s ----
    float aw[L_][3];
#pragma unroll
    for (int l = 0; l < L_; ++l) {
      float sc0 = hsum16(s_q[l * D + lane] * SKI(w, 0 * D + lane)) * 0.25f;
      float sc1 = hsum16(s_q[l * D + lane] * SKI(w, 1 * D + lane)) * 0.25f;
      float sc2 = hsum16(s_q[l * D + lane] * SKI(w, 2 * D + lane)) * 0.25f;
      float mx = fmaxf(sc0, fmaxf(sc1, sc2));
      float e0 = expf(sc0 - mx), e1 = expf(sc1 - mx), e2 = expf(sc2 - mx);
      float inv = 1.f / (e0 + e1 + e2);
      aw[l][0] = e0 * inv; aw[l][1] = e1 * inv; aw[l][2] = e2 * inv;
    }

    // ---- attn @ v ----
#pragma unroll
    for (int l = 0; l < L_; ++l)
      SAO(w, l * D + lane) = aw[l][0] * vreg[0] + aw[l][1] * vreg[1] + aw[l][2] * vreg[2];
    WB();

    // ---- out-proj + residual + LN1 -> lat1T [s][col][latent] (float4 store) ----
    float zl1[4];
#pragma unroll
    for (int l = 0; l < L_; ++l) {
      float acc = p.bo[lane];
#pragma unroll 4
      for (int i = 0; i < D; ++i) acc += SAO(w, l * D + i) * p.wo[i * D + lane];
      float x = p.latent[l * D + lane] + acc;
      float mu = wsum(x) * (1.f / D);
      float d = x - mu;
      float var = wsum(d * d) * (1.f / D);
      zl1[l] = d * rsqrtf(var + 1e-5f) * p.n1_g[lane] + p.n1_b[lane];
    }
    *reinterpret_cast<float4*>(&SL1(w, lane, 0)) = make_float4(zl1[0], zl1[1], zl1[2], zl1[3]);
  }
  __syncthreads();  // barrier #1: all lat1 ready; pool arena fully dead

  // ---- FFN1 cooperative: 512 threads, thread = (sample-pair g2, col c); weight read serves 8 outs ----
  {
    const int g2 = tid >> 8, c = tid & 255;
    float facc[2][4];
    const float bb1 = p.ffn_b1[c];
#pragma unroll
    for (int sp = 0; sp < 2; ++sp)
#pragma unroll
      for (int l = 0; l < 4; ++l) facc[sp][l] = bb1;
#pragma unroll 2
    for (int i = 0; i < D; ++i) {
      float w1v = p.ffn_w1[i * 256 + c];
#pragma unroll
      for (int sp = 0; sp < 2; ++sp) {
        float4 xl = *reinterpret_cast<const float4*>(&SL1(2 * g2 + sp, i, 0));
        facc[sp][0] += xl.x * w1v;
        facc[sp][1] += xl.y * w1v;
        facc[sp][2] += xl.z * w1v;
        facc[sp][3] += xl.w * w1v;
      }
    }
#pragma unroll
    for (int sp = 0; sp < 2; ++sp) {
      float4 hv;
      hv.x = 0.5f * facc[sp][0] * (1.f + erff(facc[sp][0] * 0.70710678118654752f));
      hv.y = 0.5f * facc[sp][1] * (1.f + erff(facc[sp][1] * 0.70710678118654752f));
      hv.z = 0.5f * facc[sp][2] * (1.f + erff(facc[sp][2] * 0.70710678118654752f));
      hv.w = 0.5f * facc[sp][3] * (1.f + erff(facc[sp][3] * 0.70710678118654752f));
      *reinterpret_cast<float4*>(&SH1(2 * g2 + sp, c, 0)) = hv;
    }
  }
  __syncthreads();  // barrier #2

  // ---- FFN2 cooperative: wave w -> (latent l = w&3, sample-pair g2 = w>>2), lane = out col ----
  {
    const int l = w & 3, g2 = w >> 2;
    float acc2[2];
    acc2[0] = p.ffn_b2[lane];
    acc2[1] = p.ffn_b2[lane];
#pragma unroll 4
    for (int m2 = 0; m2 < 256; ++m2) {
      float w2v = p.ffn_w2[m2 * D + lane];
      acc2[0] += SH1(2 * g2 + 0, m2, l) * w2v;
      acc2[1] += SH1(2 * g2 + 1, m2, l) * w2v;
    }
#pragma unroll
    for (int sp = 0; sp < 2; ++sp) {
      const int s = 2 * g2 + sp;
      float x = SL1(s, lane, l) + acc2[sp];
      float mu = wsum(x) * (1.f / D);
      float d = x - mu;
      float var = wsum(d * d) * (1.f / D);
      SL2(s, l, lane) = d * rsqrtf(var + 1e-5f) * p.n2_g[lane] + p.n2_b[lane];
    }
  }
  __syncthreads();  // barrier #3

  // ---- f = mean over latents (order l0+l1+l2+l3, as before) ----
  if (w < 4) {
    const int b = b0 + w;
    fl = 0.25f * (((SL2(w, 0, lane) + SL2(w, 1, lane)) + SL2(w, 2, lane)) + SL2(w, 3, lane));
    SF(w, lane) = fl;
    p.out[(size_t)B_ * 75 + (size_t)b * D + lane] = fl;
  }
  __syncthreads();  // barrier #4: s_f visible to view-waves

  if (w >= 4) {
    // ---- views for sample (w-4): lanes 0-31 view1, 32-63 view2 ----
    const int sv = w - 4;
    const int bs = b0 + sv;
    const float* PW = (lane < 32) ? p.p1_w : p.p2_w;
    const float* PB = (lane < 32) ? p.p1_b : p.p2_b;
    const int col = lane & 31;
    float acc = PB[col];
#pragma unroll 4
    for (int i = 0; i < D; ++i) acc += SF(sv, i) * PW[i * 32 + col];
    const size_t base = (lane < 32) ? (size_t)B_ * 139 : (size_t)B_ * 171;
    p.out[base + (size_t)bs * 32 + col] = acc;
  } else {
    const int b = b0 + w;
    // ---- router: hidden + LN + ReLU, logits via wave reductions, softmax in regs ----
    {
      float acc = p.r_b1[lane];
#pragma unroll 4
      for (int i = 0; i < D; ++i) acc += SF(w, i) * p.r_w1[i * D + lane];
      float mu = wsum(acc) * (1.f / D);
      float d = acc - mu;
      float var = wsum(d * d) * (1.f / D);
      float rr = fmaxf(d * rsqrtf(var + 1e-5f) * p.r_ln_g[lane] + p.r_ln_b[lane], 0.f);
      float l0 = wsum(rr * p.r_w2[lane * E_ + 0]) + p.r_b2[0];
      float l1 = wsum(rr * p.r_w2[lane * E_ + 1]) + p.r_b2[1];
      float l2 = wsum(rr * p.r_w2[lane * E_ + 2]) + p.r_b2[2];
      float l3 = wsum(rr * p.r_w2[lane * E_ + 3]) + p.r_b2[3];
      float mx = fmaxf(fmaxf(l0, l1), fmaxf(l2, l3));
      float e0 = expf(l0 - mx), e1 = expf(l1 - mx), e2 = expf(l2 - mx), e3 = expf(l3 - mx);
      float inv = 1.f / (e0 + e1 + e2 + e3);
      w0 = e0 * inv; w1 = e1 * inv; w2 = e2 * inv; w3 = e3 * inv;
      float wsel = (lane == 0) ? w0 : (lane == 1) ? w1 : (lane == 2) ? w2 : w3;
      if (lane < E_) p.out[(size_t)B_ * 7 + (size_t)b * E_ + lane] = wsel;
    }

    // ---- LoRA down (lanes 0-31: e = lane/8, r = lane%8) ----
    if (lane < E_ * R_) {
      const int e = lane >> 3, r = lane & 7;
      float acc = 0.f;
#pragma unroll 4
      for (int dd = 0; dd < D; ++dd) acc += SF(w, dd) * p.lora_down[e * D * R_ + dd * R_ + r];
      SDN(w, lane) = acc;
    }
    WB();

    // ---- LoRA up + expert mix -> fused ----
    float fused;
    {
      const float we4[4] = {w0, w1, w2, w3};
      float acc = 0.f;
#pragma unroll
      for (int e = 0; e < E_; ++e) {
        float up = 0.f;
#pragma unroll
        for (int r = 0; r < R_; ++r)
          up += SDN(w, e * R_ + r) * p.lora_up[e * R_ * D + r * D + lane];
        acc += we4[e] * (fl + 2.0f * up);  // SCALING = 16/8 = 2
      }
      fused = acc;
      p.out[(size_t)B_ * 11 + (size_t)b * D + lane] = fused;
    }

    // ---- classifier ----
    {
      float mu = wsum(fused) * (1.f / D);
      float d = fused - mu;
      float var = wsum(d * d) * (1.f / D);
      SCL(w, lane) = d * rsqrtf(var + 1e-5f) * p.c_ln_g[lane] + p.c_ln_b[lane];
    }
    WB();
    {
      float acc = p.c_b1[lane];
#pragma unroll 4
      for (int i = 0; i < D; ++i) acc += SCL(w, i) * p.c_w1[i * D + lane];
      float h = fmaxf(acc, 0.f);
#pragma unroll
      for (int nc = 0; nc < NC; ++nc) {
        float lg = wsum(h * p.c_w2[lane * NC + nc]) + p.c_b2[nc];
        if (lane == nc) p.out[(size_t)b * NC + nc] = lg;
      }
    }
  }
}

extern "C" void kernel_launch(void* const* d_in, const int* in_sizes, int n_in,
                              void* d_out, int out_size, void* d_ws, size_t ws_size,
                              hipStream_t stream) {
  (void)in_sizes; (void)n_in; (void)out_size; (void)d_ws; (void)ws_size;
  Params p;
  memcpy(&p, d_in, 50 * sizeof(void*));  // 50 const pointers in setup_inputs() order
  p.out = (float*)d_out;
  fused_kernel<<<dim3(B_ / 4), dim3(512), 0, stream>>>(p);
}